// Round 6
// baseline (181.357 us; speedup 1.0000x reference)
//
#include <hip/hip_runtime.h>
#include <math.h>

typedef float  f32x4 __attribute__((ext_vector_type(4)));
typedef double f64x4 __attribute__((ext_vector_type(4)));

#define H      4096
#define E      64
#define TOPK   8
#define TILE_T 32

// Pre-transpose W[e][k] (f32) into the order the main loop consumes:
//   Wb[ ((m*4 + kg)*64 + e)*4 + i ] = W[e][16m + 4kg + i]
__global__ __launch_bounds__(256)
void transpose_w(const float* __restrict__ Wg, float* __restrict__ Wb)
{
  int n = blockIdx.x * 256 + threadIdx.x;    // 64*4096 = 262144
  int e = n >> 12, k = n & 4095;
  float v = Wg[n];
  int m = k >> 4, kg = (k >> 2) & 3, i = k & 3;
  Wb[(((m * 4 + kg) * 64) + e) * 4 + i] = v;
}

// f64-exact router via v_mfma_f64_16x16x4_f64, runtime-probed readout map
// (verified R4/R5). R6: 1024-thread blocks, K split in QUARTERS across
// wave-groups -> 8 waves/SIMD (2 blocks/CU) so the MFMA pipe stays fed even
// when waves self-synchronize on vmcnt.
__global__ __launch_bounds__(1024, 8)
void moe_gate_mfma(const float* __restrict__ X, const float* __restrict__ Wb,
                   float* __restrict__ out, int n_tokens)
{
  __shared__ double Ls[TILE_T * E];   // 16 KB: f64 partial-sum + epilogue

  const int tid  = threadIdx.x;
  const int lane = tid & 63;
  const int w    = tid >> 6;      // 0..15
  const int wg   = w >> 2;        // K quarter 0..3
  const int we   = w & 3;         // expert group 16we..16we+15
  const int t0   = blockIdx.x * TILE_T;
  const int l15  = lane & 15;
  const int kg   = lane >> 4;

  // ---- probe the effective (lane,reg) -> (token,expert) readout map ----
  f64x4 z = {0.0, 0.0, 0.0, 0.0};
  f64x4 pcol = __builtin_amdgcn_mfma_f64_16x16x4f64(1.0, (double)l15, z, 0, 0, 0);
  f64x4 prow = __builtin_amdgcn_mfma_f64_16x16x4f64((double)l15, 1.0, z, 0, 0, 0);
  int qrow[4], qcol[4];
  #pragma unroll
  for (int r = 0; r < 4; ++r) {
    qrow[r] = (int)(prow[r] * 0.25 + 0.5);
    qcol[r] = (int)(pcol[r] * 0.25 + 0.5);
  }

  const int kbase = wg * (H / 4);           // 0,1024,2048,3072
  const int mbase = wg * 64;                // 64 k16-steps per quarter
  const float* xp0 = X  + (size_t)(t0 + l15) * H + kbase + 4 * kg;
  const float* xp1 = X  + (size_t)(t0 + 16 + l15) * H + kbase + 4 * kg;
  const float* bp  = Wb + (((size_t)mbase * 4 + kg) * 64 + 16 * we + l15) * 4;

  f64x4 c0 = {0.0, 0.0, 0.0, 0.0};
  f64x4 c1 = {0.0, 0.0, 0.0, 0.0};

  f32x4 a0 = *(const f32x4*)(xp0);
  f32x4 a1 = *(const f32x4*)(xp1);
  f32x4 bv = *(const f32x4*)(bp);

  #pragma unroll 4
  for (int m = 0; m < 63; ++m) {
    f32x4 na0 = *(const f32x4*)(xp0 + (m + 1) * 16);
    f32x4 na1 = *(const f32x4*)(xp1 + (m + 1) * 16);
    f32x4 nbv = *(const f32x4*)(bp + (size_t)(m + 1) * 1024);
    #pragma unroll
    for (int i = 0; i < 4; ++i) {
      double bd = (double)bv[i];
      c0 = __builtin_amdgcn_mfma_f64_16x16x4f64((double)a0[i], bd, c0, 0, 0, 0);
      c1 = __builtin_amdgcn_mfma_f64_16x16x4f64((double)a1[i], bd, c1, 0, 0, 0);
    }
    a0 = na0; a1 = na1; bv = nbv;
  }
  #pragma unroll
  for (int i = 0; i < 4; ++i) {   // last step of this quarter
    double bd = (double)bv[i];
    c0 = __builtin_amdgcn_mfma_f64_16x16x4f64((double)a0[i], bd, c0, 0, 0, 0);
    c1 = __builtin_amdgcn_mfma_f64_16x16x4f64((double)a1[i], bd, c1, 0, 0, 0);
  }

  // ---- combine K-quarters in LDS (wg0 writes, wg1..3 add in turn) ----
  if (wg == 0) {
    #pragma unroll
    for (int r = 0; r < 4; ++r) {
      Ls[qrow[r] * E + 16 * we + qcol[r]]        = c0[r];
      Ls[(16 + qrow[r]) * E + 16 * we + qcol[r]] = c1[r];
    }
  }
  __syncthreads();
  #pragma unroll
  for (int g = 1; g < 4; ++g) {
    if (wg == g) {
      #pragma unroll
      for (int r = 0; r < 4; ++r) {
        Ls[qrow[r] * E + 16 * we + qcol[r]]        += c0[r];
        Ls[(16 + qrow[r]) * E + 16 * we + qcol[r]] += c1[r];
      }
    }
    __syncthreads();
  }

  // ---- per-token softmax + top-8 on f64 logits (verified R2/R4/R5) ----
  // 16 waves x 2 tokens = 32 tokens
  for (int tt = 0; tt < 2; tt++) {
    int t = w * 2 + tt;
    double val = Ls[t * E + lane];

    double mx = val;
    #pragma unroll
    for (int off = 32; off >= 1; off >>= 1)
      mx = fmax(mx, __shfl_xor(mx, off));

    double p = exp(val - mx);
    double S = p;
    #pragma unroll
    for (int off = 32; off >= 1; off >>= 1)
      S += __shfl_xor(S, off);

    double cur = val;
    double myw = 0.0; int myidx = 0;
    double psum = 0.0;
    #pragma unroll
    for (int r = 0; r < TOPK; r++) {
      double v = cur; int ii = lane;
      #pragma unroll
      for (int off = 32; off >= 1; off >>= 1) {
        double ov = __shfl_xor(v, off);
        int    oi = __shfl_xor(ii, off);
        if (ov > v || (ov == v && oi < ii)) { v = ov; ii = oi; }
      }
      double pw = __shfl(p, ii);
      psum += pw;
      if (lane == r) { myw = pw; myidx = ii; }
      if (lane == ii) cur = -INFINITY;
    }
    double denom = psum / S + 1e-20;
    if (lane < TOPK) {
      size_t gt = (size_t)(t0 + t);
      out[gt * TOPK + lane] = (float)((myw / S) / denom);
      out[(size_t)n_tokens * TOPK + gt * TOPK + lane] = (float)myidx;
    }
  }
}

extern "C" void kernel_launch(void* const* d_in, const int* in_sizes, int n_in,
                              void* d_out, int out_size, void* d_ws, size_t ws_size,
                              hipStream_t stream)
{
  const float* X  = (const float*)d_in[0];
  const float* Wg = (const float*)d_in[1];
  float* out = (float*)d_out;
  float* Wb  = (float*)d_ws;            // 1 MB scratch
  int n_tokens = in_sizes[0] / H;       // 16384

  transpose_w<<<(E * H) / 256, 256, 0, stream>>>(Wg, Wb);
  moe_gate_mfma<<<n_tokens / TILE_T, 1024, 0, stream>>>(X, Wb, out, n_tokens);
}